// Round 1
// baseline (851.113 us; speedup 1.0000x reference)
//
#include <hip/hip_runtime.h>
#include <math.h>

#define IMG_H 64
#define IMG_W 64
#define NBATCH 16
#define C_IN 64
#define C_MID 64
#define C_BC 96
#define C_OUT 128

// ---------------------------------------------------------------------------
// conv3x3 (pad 1) + BN + tanh, NCHW fp32.
// Block: 256 threads = 32 cols x 8 row-groups (4 rows each) over a 32x32 tile.
// Grid: (4 tiles, Cout/8 groups, N). Input channels staged 8-at-a-time in LDS.
// Weights read with uniform indices -> scalar loads (SGPR), no LDS needed.
// ---------------------------------------------------------------------------
template <int CIN>
__global__ __launch_bounds__(256) void conv_bn_tanh(
    const float* __restrict__ in, const float* __restrict__ w,
    const float* __restrict__ bias, const float* __restrict__ gamma,
    const float* __restrict__ beta, const float* __restrict__ mean,
    const float* __restrict__ var, float* __restrict__ out, int Cout) {
  __shared__ float xs[8 * 34 * 36];  // 8 ch, 34 rows, 36-col padded stride

  const int t = threadIdx.x;
  const int tile = blockIdx.x;  // 0..3  (2x2 tiles of 32x32)
  const int ocg = blockIdx.y;   // output-channel group of 8
  const int n = blockIdx.z;

  const int x0 = (tile & 1) * 32;
  const int y0 = (tile >> 1) * 32;
  const int tx = t & 31;   // col within tile
  const int tyg = t >> 5;  // row group (4 rows each)
  const int py0 = tyg * 4;

  float acc[4][8];
#pragma unroll
  for (int p = 0; p < 4; ++p)
#pragma unroll
    for (int o = 0; o < 8; ++o) acc[p][o] = 0.f;

  const float* inn = in + (size_t)n * CIN * IMG_H * IMG_W;

  for (int icg = 0; icg < CIN / 8; ++icg) {
    __syncthreads();
    // stage 8 channels with halo: rows y0-1..y0+32, cols x0-1..x0+32 (34x34)
    for (int idx = t; idx < 8 * 34 * 34; idx += 256) {
      int c = idx / (34 * 34);
      int rem = idx - c * (34 * 34);
      int r = rem / 34;
      int cc = rem - r * 34;
      int gy = y0 - 1 + r, gx = x0 - 1 + cc;
      float v = 0.f;
      if (gy >= 0 && gy < IMG_H && gx >= 0 && gx < IMG_W)
        v = inn[(size_t)(icg * 8 + c) * (IMG_H * IMG_W) + gy * IMG_W + gx];
      xs[c * (34 * 36) + r * 36 + cc] = v;
    }
    __syncthreads();
#pragma unroll
    for (int ic = 0; ic < 8; ++ic) {
      // 4 vertical pixels share a 6x3 input window
      float xv[6][3];
#pragma unroll
      for (int rr = 0; rr < 6; ++rr)
#pragma unroll
        for (int cc = 0; cc < 3; ++cc)
          xv[rr][cc] = xs[ic * (34 * 36) + (py0 + rr) * 36 + tx + cc];
#pragma unroll
      for (int o = 0; o < 8; ++o) {
        const float* wp = w + ((size_t)(ocg * 8 + o) * CIN + icg * 8 + ic) * 9;
        float wk[9];
#pragma unroll
        for (int k = 0; k < 9; ++k) wk[k] = wp[k];  // uniform -> s_load
#pragma unroll
        for (int p = 0; p < 4; ++p)
#pragma unroll
          for (int i = 0; i < 3; ++i)
#pragma unroll
            for (int j = 0; j < 3; ++j)
              acc[p][o] = fmaf(xv[p + i][j], wk[i * 3 + j], acc[p][o]);
      }
    }
  }

#pragma unroll
  for (int o = 0; o < 8; ++o) {
    int oc = ocg * 8 + o;
    float s = gamma[oc] * rsqrtf(var[oc] + 1e-5f);
    float bb = (bias[oc] - mean[oc]) * s + beta[oc];
#pragma unroll
    for (int p = 0; p < 4; ++p) {
      float v = tanhf(acc[p][o] * s + bb);
      out[((size_t)n * Cout + oc) * (IMG_H * IMG_W) + (y0 + py0 + p) * IMG_W +
          x0 + tx] = v;
    }
  }
}

// ---------------------------------------------------------------------------
// Fused: atoms + bases_out + 1x1 coef contraction.
// For pixel (p,q):   (p indexes x rows / output last dim, q x cols / out 3rd)
//   xb[c][t]      = sum_k x[p+di-1, q+dj-1][c] * bases[t][k]
//   bases_out[d=c*16+f] = sum_t xb[c][t] * bc[f*6+t][h=q, w=p]
//   out[n,o,q,p]  = sum_d bases_out[d] * coef[o][d]
// Block: 256 threads, one (n, 8x8 pixel tile). K-loop over c (chunk = 16 f).
// px index inside tile = qx*8 + py  (py fast -> float4 output stores).
// ---------------------------------------------------------------------------
__global__ __launch_bounds__(256) void adconv_final(
    const float* __restrict__ x, const float* __restrict__ bc,
    const float* __restrict__ bases, const float* __restrict__ coef,
    float* __restrict__ out) {
  __shared__ float xs[64 * 100];   // [c][r*10+col], 10x10 halo region
  __shared__ float bcs[96 * 65];   // [ch][px], padded
  __shared__ float As[16 * 68];    // [f][px], padded
  __shared__ float Bs[16 * 132];   // [kk][o], padded

  const int t = threadIdx.x;
  const int tile = blockIdx.x;  // 0..63
  const int n = blockIdx.y;
  const int q0 = (tile & 7) * 8;   // col origin
  const int p0 = (tile >> 3) * 8;  // row origin

  // bases -> registers (uniform loads -> SGPRs)
  float bs[54];
#pragma unroll
  for (int i = 0; i < 54; ++i) bs[i] = bases[i];

  // stage x patches: 64 ch x 10x10 (rows p0-1.., cols q0-1..)
  const float* xn = x + (size_t)n * C_IN * IMG_H * IMG_W;
  for (int idx = t; idx < 64 * 100; idx += 256) {
    int c = idx / 100;
    int rem = idx - c * 100;
    int r = rem / 10, col = rem - r * 10;
    int gp = p0 - 1 + r, gq = q0 - 1 + col;
    float v = 0.f;
    if (gp >= 0 && gp < IMG_H && gq >= 0 && gq < IMG_W)
      v = xn[c * (IMG_H * IMG_W) + gp * IMG_W + gq];
    xs[c * 100 + r * 10 + col] = v;
  }

  // stage bc tile: bcs[ch][px] = bc[n][ch][h=q0+qx][w=p0+py]
  const float* bcn = bc + (size_t)n * C_BC * IMG_H * IMG_W;
  for (int idx = t; idx < 96 * 64; idx += 256) {
    int ch = idx >> 6;
    int px = idx & 63;
    int qx = px >> 3, py = px & 7;
    bcs[ch * 65 + px] = bcn[ch * (IMG_H * IMG_W) + (q0 + qx) * IMG_W + p0 + py];
  }

  // thread roles
  const int pxg = (t & 15) * 4;  // GEMM: 4 consecutive px
  const int og = (t >> 4) * 8;   // GEMM: 8 consecutive o
  const int mypx = t >> 2;       // A-step: my pixel
  const int f0 = (t & 3) * 4;    // A-step: my 4 f values
  const int qx_a = mypx >> 3, py_a = mypx & 7;

  float acc[4][8];
#pragma unroll
  for (int p = 0; p < 4; ++p)
#pragma unroll
    for (int m = 0; m < 8; ++m) acc[p][m] = 0.f;

  for (int c = 0; c < C_IN; ++c) {
    __syncthreads();  // previous GEMM done; xs/bcs ready on first iter
    // stage coef chunk: Bs[kk][o] = coef[o][c*16+kk]
#pragma unroll
    for (int it = 0; it < 8; ++it) {
      int e = it * 256 + t;
      int o = e >> 4, kk = e & 15;
      Bs[kk * 132 + o] = coef[(size_t)o * 1024 + c * 16 + kk];
    }
    // xb[t'] = sum_k patch(mypx, c, k) * bases[t'][k]
    float xb[6];
#pragma unroll
    for (int tt = 0; tt < 6; ++tt) xb[tt] = 0.f;
#pragma unroll
    for (int i = 0; i < 3; ++i)
#pragma unroll
      for (int j = 0; j < 3; ++j) {
        float pv = xs[c * 100 + (py_a + i) * 10 + (qx_a + j)];
#pragma unroll
        for (int tt = 0; tt < 6; ++tt)
          xb[tt] = fmaf(pv, bs[tt * 9 + i * 3 + j], xb[tt]);
      }
    // A[f][mypx] = sum_t xb[t] * bcs[f*6+t][mypx]
#pragma unroll
    for (int jf = 0; jf < 4; ++jf) {
      int f = f0 + jf;
      float a = 0.f;
#pragma unroll
      for (int tt = 0; tt < 6; ++tt)
        a = fmaf(xb[tt], bcs[(f * 6 + tt) * 65 + mypx], a);
      As[f * 68 + mypx] = a;
    }
    __syncthreads();
    // GEMM: acc[p][m] += As[kk][pxg+p] * Bs[kk][og+m]
#pragma unroll
    for (int kk = 0; kk < 16; ++kk) {
      float4 av = *(const float4*)&As[kk * 68 + pxg];
      float4 b0 = *(const float4*)&Bs[kk * 132 + og];
      float4 b1 = *(const float4*)&Bs[kk * 132 + og + 4];
      float a4[4] = {av.x, av.y, av.z, av.w};
      float bv[8] = {b0.x, b0.y, b0.z, b0.w, b1.x, b1.y, b1.z, b1.w};
#pragma unroll
      for (int m = 0; m < 8; ++m)
#pragma unroll
        for (int p = 0; p < 4; ++p)
          acc[p][m] = fmaf(a4[p], bv[m], acc[p][m]);
    }
  }

  // epilogue: out[n][o][q0+qx][p0+py0..py0+3]  (float4 along fast dim)
  const int qx = pxg >> 3;
  const int py0 = pxg & 7;
  float* outn = out + (size_t)n * C_OUT * IMG_H * IMG_W;
#pragma unroll
  for (int m = 0; m < 8; ++m) {
    int o = og + m;
    float4 v = make_float4(acc[0][m], acc[1][m], acc[2][m], acc[3][m]);
    *(float4*)&outn[(o * IMG_W + q0 + qx) * IMG_H + p0 + py0] = v;
  }
}

// ---------------------------------------------------------------------------
extern "C" void kernel_launch(void* const* d_in, const int* in_sizes, int n_in,
                              void* d_out, int out_size, void* d_ws,
                              size_t ws_size, hipStream_t stream) {
  const float* x = (const float*)d_in[0];
  const float* conv1_w = (const float*)d_in[1];
  const float* conv1_b = (const float*)d_in[2];
  const float* bn1_g = (const float*)d_in[3];
  const float* bn1_b = (const float*)d_in[4];
  const float* bn1_m = (const float*)d_in[5];
  const float* bn1_v = (const float*)d_in[6];
  const float* conv2_w = (const float*)d_in[7];
  const float* conv2_b = (const float*)d_in[8];
  const float* bn2_g = (const float*)d_in[9];
  const float* bn2_b = (const float*)d_in[10];
  const float* bn2_m = (const float*)d_in[11];
  const float* bn2_v = (const float*)d_in[12];
  const float* bases = (const float*)d_in[13];
  const float* coef = (const float*)d_in[14];
  float* out = (float*)d_out;

  float* h = (float*)d_ws;                              // 16*64*64*64 floats
  float* bc = h + (size_t)NBATCH * C_MID * IMG_H * IMG_W;  // 16*96*64*64 floats

  conv_bn_tanh<C_IN><<<dim3(4, C_MID / 8, NBATCH), 256, 0, stream>>>(
      x, conv1_w, conv1_b, bn1_g, bn1_b, bn1_m, bn1_v, h, C_MID);
  conv_bn_tanh<C_MID><<<dim3(4, C_BC / 8, NBATCH), 256, 0, stream>>>(
      h, conv2_w, conv2_b, bn2_g, bn2_b, bn2_m, bn2_v, bc, C_BC);
  adconv_final<<<dim3(64, NBATCH), 256, 0, stream>>>(x, bc, bases, coef, out);
}

// Round 3
// 246.755 us; speedup vs baseline: 3.4492x; 3.4492x over previous
//
#include <hip/hip_runtime.h>
#include <math.h>
#include <string.h>

#define IMG 64
#define NBATCH 16
#define C_IN 64
#define C_MID 64
#define C_BC 96
#define C_OUT 128

typedef __attribute__((ext_vector_type(8))) short short8;
typedef __attribute__((ext_vector_type(4))) float floatx4;
#define MFMA16(a, b, c) __builtin_amdgcn_mfma_f32_16x16x32_bf16(a, b, c, 0, 0, 0)

// round-to-nearest-even f32 -> bf16 (bit arithmetic; no hip bf16 class)
__device__ __forceinline__ unsigned short f2bf(float f) {
  unsigned int u = __float_as_uint(f);
  unsigned int rounding = ((u >> 16) & 1u) + 0x7fffu;
  return (unsigned short)((u + rounding) >> 16);
}
__device__ __forceinline__ unsigned int packbf2(float a, float b) {
  return (unsigned int)f2bf(a) | ((unsigned int)f2bf(b) << 16);
}
__device__ __forceinline__ float bf2f(unsigned short u) {
  return __uint_as_float(((unsigned int)u) << 16);
}

// ---------------------------------------------------------------------------
// prep: convert weights to [off][oc][ic] bf16 and coef to bf16.
// ---------------------------------------------------------------------------
__global__ void prep_kernel(const float* __restrict__ w1,
                            const float* __restrict__ w2,
                            const float* __restrict__ coef,
                            unsigned short* __restrict__ wb1,
                            unsigned short* __restrict__ wb2,
                            unsigned short* __restrict__ coefb) {
  int i = blockIdx.x * 256 + threadIdx.x;
  if (i < 131072) coefb[i] = f2bf(coef[i]);
  if (i < 36864) {  // [kk][64][64]
    int kk = i / 4096, rem = i - kk * 4096;
    int oc = rem >> 6, ic = rem & 63;
    wb1[i] = f2bf(w1[(oc * 64 + ic) * 9 + kk]);
  }
  if (i < 55296) {  // [kk][96][64]
    int kk = i / 6144, rem = i - kk * 6144;
    int oc = rem >> 6, ic = rem & 63;
    wb2[i] = f2bf(w2[(oc * 64 + ic) * 9 + kk]);
  }
}

// ---------------------------------------------------------------------------
// conv3x3 + BN + tanh via MFMA implicit GEMM.
// Block: 256 thr, M=128 px (2 image rows) x COUT. LDS: 4 rows x 66 cols x ic.
// IN_F32: input fp32 NCHW (conv1); else bf16 NHWC. Output bf16 NHWC.
// NSW = nsub per wave-column (COUT/16/2).
// ---------------------------------------------------------------------------
template <int COUT, int NSW, bool IN_F32>
__global__ __launch_bounds__(256) void conv_mfma(
    const void* __restrict__ inp, const unsigned short* __restrict__ wb,
    const float* __restrict__ bias, const float* __restrict__ gamma,
    const float* __restrict__ beta, const float* __restrict__ mean,
    const float* __restrict__ var, unsigned short* __restrict__ outp) {
  __shared__ unsigned short xr[4 * 66 * 72];  // [r][col][ic], stride 72

  const int t = threadIdx.x;
  const int y0 = blockIdx.x * 2;
  const int n = blockIdx.y;

  if (IN_F32) {
    const float* in = (const float*)inp + (size_t)n * 64 * 4096;
#pragma unroll
    for (int it = 0; it < 16; ++it) {
      int v = it * 256 + t;  // r(2b) ic(6b) x4(4b)
      int r = v >> 10, ic = (v >> 4) & 63, x4 = v & 15;
      int gy = y0 - 1 + r;
      float4 val = {0.f, 0.f, 0.f, 0.f};
      if ((unsigned)gy < 64u)
        val = *(const float4*)&in[ic * 4096 + gy * 64 + x4 * 4];
      int base = (r * 66 + x4 * 4 + 1) * 72 + ic;
      xr[base] = f2bf(val.x);
      xr[base + 72] = f2bf(val.y);
      xr[base + 144] = f2bf(val.z);
      xr[base + 216] = f2bf(val.w);
    }
  } else {
    const unsigned short* in = (const unsigned short*)inp + (size_t)n * 4096 * 64;
#pragma unroll
    for (int it = 0; it < 8; ++it) {
      int v = it * 256 + t;  // r(2b) x(6b) ic8(3b)
      int r = v >> 9, xx = (v >> 3) & 63, ic8 = v & 7;
      int gy = y0 - 1 + r;
      uint4 val = {0u, 0u, 0u, 0u};
      if ((unsigned)gy < 64u)
        val = *(const uint4*)&in[((size_t)gy * 64 + xx) * 64 + ic8 * 8];
      *(uint4*)&xr[(r * 66 + xx + 1) * 72 + ic8 * 8] = val;
    }
  }
  {  // zero halo columns
    int r = t >> 6, ic = t & 63;
    xr[(r * 66) * 72 + ic] = 0;
    xr[(r * 66 + 65) * 72 + ic] = 0;
  }
  __syncthreads();

  const int lane = t & 63, w = t >> 6;
  const int wi = w & 1, wj = w >> 1;  // msub 4*wi.., nsub wj*NSW..
  const int lm = lane & 15, lq = lane >> 4;

  floatx4 acc[4][NSW];
#pragma unroll
  for (int s = 0; s < 4; ++s)
#pragma unroll
    for (int u = 0; u < NSW; ++u) acc[s][u] = floatx4{0.f, 0.f, 0.f, 0.f};

#pragma unroll
  for (int off = 0; off < 9; ++off) {
    const int di = off / 3, dj = off % 3;
#pragma unroll
    for (int kc = 0; kc < 2; ++kc) {
      const int k0 = kc * 32 + lq * 8;
      short8 a[4];
#pragma unroll
      for (int s = 0; s < 4; ++s) {
        int msub = wi * 4 + s;
        int yoff = msub >> 2;
        int xx = (msub & 3) * 16 + lm;
        a[s] = *(const short8*)&xr[((yoff + di) * 66 + xx + dj) * 72 + k0];
      }
#pragma unroll
      for (int u = 0; u < NSW; ++u) {
        int oc = (wj * NSW + u) * 16 + lm;
        short8 b = *(const short8*)&wb[((size_t)off * COUT + oc) * 64 + k0];
#pragma unroll
        for (int s = 0; s < 4; ++s) acc[s][u] = MFMA16(a[s], b, acc[s][u]);
      }
    }
  }

  // epilogue: BN + tanh, store NHWC bf16
  unsigned short* outn = outp + (size_t)n * 4096 * COUT;
#pragma unroll
  for (int u = 0; u < NSW; ++u) {
    int oc = (wj * NSW + u) * 16 + lm;
    float sc = gamma[oc] * rsqrtf(var[oc] + 1e-5f);
    float sh = (bias[oc] - mean[oc]) * sc + beta[oc];
#pragma unroll
    for (int s = 0; s < 4; ++s) {
      int m0 = (wi * 4 + s) * 16 + lq * 4;
#pragma unroll
      for (int r = 0; r < 4; ++r) {
        int m = m0 + r;
        int y = y0 + (m >> 6), xx = m & 63;
        outn[((size_t)y * 64 + xx) * COUT + oc] =
            f2bf(tanhf(acc[s][u][r] * sc + sh));
      }
    }
  }
}

// ---------------------------------------------------------------------------
// Fused atoms + bases_out + 1x1 coef contraction, MFMA GEMM over K=1024.
// Block: 256 thr, one (n, 8x8 px tile). 16 rounds x 64-K chunks.
// A-build: thread (px=t>>2, cq=t&3) computes c = rd*4+cq, all 16 f.
// ---------------------------------------------------------------------------
__global__ __launch_bounds__(256) void adconv_final(
    const float* __restrict__ x, const unsigned short* __restrict__ bc,
    const float* __restrict__ bases, const unsigned short* __restrict__ coefb,
    float* __restrict__ out) {
  __shared__ union {
    struct {
      unsigned short xs[64 * 100];  // [c][(p)*10 + (q)] bf16, 10x10 halo
      float bcs[64 * 100];          // [px][ch] fp32, pad to 100
      uint4 As2[64 * 8];            // [px][unit ^ (px&7)] : 64 bf16 per px
    } s;
    float ot[128 * 68];  // epilogue transpose [oc][px]
  } sm;

  const int t = threadIdx.x;
  const int tile = blockIdx.x;
  const int n = blockIdx.y;
  const int q0 = (tile & 7) * 8, p0 = (tile >> 3) * 8;

  // bases -> uniform regs (SGPRs)
  float bs[54];
#pragma unroll
  for (int i = 0; i < 54; ++i) bs[i] = bases[i];

  // stage x patches as bf16: [c][10x10]
  const float* xn = x + (size_t)n * 64 * 4096;
#pragma unroll
  for (int it = 0; it < 25; ++it) {
    int idx = it * 256 + t;
    int c = idx / 100;
    int rem = idx - c * 100;
    int r = rem / 10, col = rem - r * 10;
    int gp = p0 - 1 + r, gq = q0 - 1 + col;
    float v = 0.f;
    if ((unsigned)gp < 64u && (unsigned)gq < 64u) v = xn[c * 4096 + gp * 64 + gq];
    sm.s.xs[idx] = f2bf(v);
  }
  // stage bc tile: bcs[px][ch] fp32 from NHWC bf16
  {
    int px = t >> 2, cq3 = t & 3;
    int qx = px >> 3, py = px & 7;
    const unsigned short* bp =
        bc + ((size_t)n * 4096 + (q0 + qx) * 64 + (p0 + py)) * 96 + cq3 * 24;
    float* dst = &sm.s.bcs[px * 100 + cq3 * 24];
#pragma unroll
    for (int j = 0; j < 3; ++j) {
      uint4 v = *(const uint4*)(bp + j * 8);
      unsigned int uu[4] = {v.x, v.y, v.z, v.w};
#pragma unroll
      for (int e = 0; e < 4; ++e) {
        dst[j * 8 + e * 2] = __uint_as_float(uu[e] << 16);
        dst[j * 8 + e * 2 + 1] = __uint_as_float(uu[e] & 0xffff0000u);
      }
    }
  }

  const int lane = t & 63, w = t >> 6;
  const int wi = w & 1, wj = w >> 1;  // msub 2*wi..,  nsub 4*wj..
  const int lm = lane & 15, lq = lane >> 4;
  const int px_a = t >> 2, cq = t & 3;
  const int qx_a = px_a >> 3, py_a = px_a & 7;

  floatx4 acc[2][4];
#pragma unroll
  for (int s = 0; s < 2; ++s)
#pragma unroll
    for (int u = 0; u < 4; ++u) acc[s][u] = floatx4{0.f, 0.f, 0.f, 0.f};

  for (int rd = 0; rd < 16; ++rd) {
    __syncthreads();  // As2 free (prev GEMM done); staging visible at rd=0
    // ---- A-build: c = rd*4+cq, all 16 f ----
    const int c = rd * 4 + cq;
    float pv[9];
#pragma unroll
    for (int i = 0; i < 3; ++i)
#pragma unroll
      for (int j = 0; j < 3; ++j)
        pv[i * 3 + j] = bf2f(sm.s.xs[c * 100 + (py_a + i) * 10 + qx_a + j]);
    float xb[6];
#pragma unroll
    for (int tt = 0; tt < 6; ++tt) {
      float a = 0.f;
#pragma unroll
      for (int k = 0; k < 9; ++k) a = fmaf(pv[k], bs[tt * 9 + k], a);
      xb[tt] = a;
    }
    const float* brow = &sm.s.bcs[px_a * 100];
    unsigned int ovals[8];
#pragma unroll
    for (int fp = 0; fp < 8; ++fp) {
      float4 b0 = *(const float4*)(brow + fp * 12);
      float4 b1 = *(const float4*)(brow + fp * 12 + 4);
      float4 b2 = *(const float4*)(brow + fp * 12 + 8);
      float e0 = b0.x * xb[0];
      e0 = fmaf(b0.y, xb[1], e0); e0 = fmaf(b0.z, xb[2], e0);
      e0 = fmaf(b0.w, xb[3], e0); e0 = fmaf(b1.x, xb[4], e0);
      e0 = fmaf(b1.y, xb[5], e0);
      float e1 = b1.z * xb[0];
      e1 = fmaf(b1.w, xb[1], e1); e1 = fmaf(b2.x, xb[2], e1);
      e1 = fmaf(b2.y, xb[3], e1); e1 = fmaf(b2.z, xb[4], e1);
      e1 = fmaf(b2.w, xb[5], e1);
      ovals[fp] = packbf2(e0, e1);
    }
    {
      const int key = px_a & 7;
      uint4 w0 = {ovals[0], ovals[1], ovals[2], ovals[3]};
      uint4 w1 = {ovals[4], ovals[5], ovals[6], ovals[7]};
      sm.s.As2[px_a * 8 + ((cq * 2) ^ key)] = w0;
      sm.s.As2[px_a * 8 + ((cq * 2 + 1) ^ key)] = w1;
    }
    __syncthreads();
    // ---- GEMM: 2 kc x (2 msub x 4 nsub) MFMA ----
#pragma unroll
    for (int kc = 0; kc < 2; ++kc) {
      short8 a[2];
#pragma unroll
      for (int s = 0; s < 2; ++s) {
        int px = (wi * 2 + s) * 16 + lm;
        int unit = (kc * 4 + lq) ^ (px & 7);
        a[s] = *(const short8*)&sm.s.As2[px * 8 + unit];
      }
#pragma unroll
      for (int u = 0; u < 4; ++u) {
        int oc = (wj * 4 + u) * 16 + lm;
        const unsigned short* bp =
            coefb + (size_t)oc * 1024 + rd * 64 + kc * 32 + lq * 8;
        short8 b = *(const short8*)bp;
        acc[0][u] = MFMA16(a[0], b, acc[0][u]);
        acc[1][u] = MFMA16(a[1], b, acc[1][u]);
      }
    }
  }

  // ---- epilogue: transpose via LDS, coalesced stores ----
  __syncthreads();
#pragma unroll
  for (int s = 0; s < 2; ++s)
#pragma unroll
    for (int u = 0; u < 4; ++u) {
      int oc = (wj * 4 + u) * 16 + lm;
      int pxb = (wi * 2 + s) * 16 + lq * 4;
#pragma unroll
      for (int r = 0; r < 4; ++r) sm.ot[oc * 68 + pxb + r] = acc[s][u][r];
    }
  __syncthreads();
  float* outn = out + (size_t)n * 128 * 4096;
#pragma unroll
  for (int i = 0; i < 4; ++i) {
    int cid = i * 256 + t;  // 128 oc x 8 qx
    int oc = cid >> 3, qx = cid & 7;
    float4 v0 = *(float4*)&sm.ot[oc * 68 + qx * 8];
    float4 v1 = *(float4*)&sm.ot[oc * 68 + qx * 8 + 4];
    float* op = &outn[((size_t)oc * 64 + q0 + qx) * 64 + p0];
    *(float4*)op = v0;
    *(float4*)(op + 4) = v1;
  }
}

// ---------------------------------------------------------------------------
extern "C" void kernel_launch(void* const* d_in, const int* in_sizes, int n_in,
                              void* d_out, int out_size, void* d_ws,
                              size_t ws_size, hipStream_t stream) {
  const float* x = (const float*)d_in[0];
  const float* conv1_w = (const float*)d_in[1];
  const float* conv1_b = (const float*)d_in[2];
  const float* bn1_g = (const float*)d_in[3];
  const float* bn1_b = (const float*)d_in[4];
  const float* bn1_m = (const float*)d_in[5];
  const float* bn1_v = (const float*)d_in[6];
  const float* conv2_w = (const float*)d_in[7];
  const float* conv2_b = (const float*)d_in[8];
  const float* bn2_g = (const float*)d_in[9];
  const float* bn2_b = (const float*)d_in[10];
  const float* bn2_m = (const float*)d_in[11];
  const float* bn2_v = (const float*)d_in[12];
  const float* bases = (const float*)d_in[13];
  const float* coef = (const float*)d_in[14];
  float* out = (float*)d_out;

  char* ws = (char*)d_ws;
  unsigned short* h = (unsigned short*)(ws);              // 8,388,608 B
  unsigned short* bc = (unsigned short*)(ws + 8388608);   // 12,582,912 B
  unsigned short* wb1 = (unsigned short*)(ws + 20971520); // 73,728 B
  unsigned short* wb2 = (unsigned short*)(ws + 21045248); // 110,592 B
  unsigned short* coefb = (unsigned short*)(ws + 21155840); // 262,144 B

  prep_kernel<<<512, 256, 0, stream>>>(conv1_w, conv2_w, coef, wb1, wb2, coefb);
  conv_mfma<64, 2, true><<<dim3(32, NBATCH), 256, 0, stream>>>(
      x, wb1, conv1_b, bn1_g, bn1_b, bn1_m, bn1_v, h);
  conv_mfma<96, 3, false><<<dim3(32, NBATCH), 256, 0, stream>>>(
      h, wb2, conv2_b, bn2_g, bn2_b, bn2_m, bn2_v, bc);
  adconv_final<<<dim3(64, NBATCH), 256, 0, stream>>>(x, bc, bases, coefb, out);
}

// Round 4
// 237.079 us; speedup vs baseline: 3.5900x; 1.0408x over previous
//
#include <hip/hip_runtime.h>
#include <math.h>
#include <string.h>

#define IMG 64
#define NBATCH 16
#define C_IN 64
#define C_MID 64
#define C_BC 96
#define C_OUT 128

typedef __attribute__((ext_vector_type(8))) short short8;
typedef __attribute__((ext_vector_type(4))) float floatx4;
#define MFMA16(a, b, c) __builtin_amdgcn_mfma_f32_16x16x32_bf16(a, b, c, 0, 0, 0)

// round-to-nearest-even f32 -> bf16 (bit arithmetic; no hip bf16 class)
__device__ __forceinline__ unsigned short f2bf(float f) {
  unsigned int u = __float_as_uint(f);
  unsigned int rounding = ((u >> 16) & 1u) + 0x7fffu;
  return (unsigned short)((u + rounding) >> 16);
}
__device__ __forceinline__ unsigned int packbf2(float a, float b) {
  return (unsigned int)f2bf(a) | ((unsigned int)f2bf(b) << 16);
}
__device__ __forceinline__ float bflo(unsigned int u) {
  return __uint_as_float(u << 16);
}
__device__ __forceinline__ float bfhi(unsigned int u) {
  return __uint_as_float(u & 0xffff0000u);
}
// branch-free tanh: 1 - 2/(e^{2x}+1); saturates correctly for large |x|
__device__ __forceinline__ float fast_tanh(float x) {
  float e = __expf(2.f * x);
  return 1.f - 2.f / (e + 1.f);
}

// ---------------------------------------------------------------------------
// prep: convert weights to [off][oc][ic] bf16 and coef to bf16.
// ---------------------------------------------------------------------------
__global__ void prep_kernel(const float* __restrict__ w1,
                            const float* __restrict__ w2,
                            const float* __restrict__ coef,
                            unsigned short* __restrict__ wb1,
                            unsigned short* __restrict__ wb2,
                            unsigned short* __restrict__ coefb) {
  int i = blockIdx.x * 256 + threadIdx.x;
  if (i < 131072) coefb[i] = f2bf(coef[i]);
  if (i < 36864) {  // [kk][64][64]
    int kk = i / 4096, rem = i - kk * 4096;
    int oc = rem >> 6, ic = rem & 63;
    wb1[i] = f2bf(w1[(oc * 64 + ic) * 9 + kk]);
  }
  if (i < 55296) {  // [kk][96][64]
    int kk = i / 6144, rem = i - kk * 6144;
    int oc = rem >> 6, ic = rem & 63;
    wb2[i] = f2bf(w2[(oc * 64 + ic) * 9 + kk]);
  }
}

// ---------------------------------------------------------------------------
// conv3x3 + BN + tanh via MFMA implicit GEMM, 1 image row per block.
// Block: 256 thr, M=64 px x COUT. Grid (64 rows, N) = 1024 blocks -> 4/CU.
// LDS: 3 rows x 66 cols x 64 ic bf16 (28.5 KB).
// ---------------------------------------------------------------------------
template <int COUT, int NSW, bool IN_F32>
__global__ __launch_bounds__(256) void conv_mfma(
    const void* __restrict__ inp, const unsigned short* __restrict__ wb,
    const float* __restrict__ bias, const float* __restrict__ gamma,
    const float* __restrict__ beta, const float* __restrict__ mean,
    const float* __restrict__ var, unsigned short* __restrict__ outp) {
  __shared__ unsigned short xr[3 * 66 * 72];  // [r][col][ic], stride 72

  const int t = threadIdx.x;
  const int y0 = blockIdx.x;
  const int n = blockIdx.y;

  if (IN_F32) {
    const float* in = (const float*)inp + (size_t)n * 64 * 4096;
#pragma unroll
    for (int it = 0; it < 12; ++it) {
      int v = it * 256 + t;  // r(0..2) ic(6b) x4(4b)
      int r = v >> 10, ic = (v >> 4) & 63, x4 = v & 15;
      int gy = y0 - 1 + r;
      float4 val = {0.f, 0.f, 0.f, 0.f};
      if ((unsigned)gy < 64u)
        val = *(const float4*)&in[ic * 4096 + gy * 64 + x4 * 4];
      int base = (r * 66 + x4 * 4 + 1) * 72 + ic;
      xr[base] = f2bf(val.x);
      xr[base + 72] = f2bf(val.y);
      xr[base + 144] = f2bf(val.z);
      xr[base + 216] = f2bf(val.w);
    }
  } else {
    const unsigned short* in = (const unsigned short*)inp + (size_t)n * 4096 * 64;
#pragma unroll
    for (int it = 0; it < 6; ++it) {
      int v = it * 256 + t;  // r(0..2) x(6b) ic8(3b)
      int r = v >> 9, xx = (v >> 3) & 63, ic8 = v & 7;
      int gy = y0 - 1 + r;
      uint4 val = {0u, 0u, 0u, 0u};
      if ((unsigned)gy < 64u)
        val = *(const uint4*)&in[((size_t)gy * 64 + xx) * 64 + ic8 * 8];
      *(uint4*)&xr[(r * 66 + xx + 1) * 72 + ic8 * 8] = val;
    }
  }
  if (t < 192) {  // zero halo columns
    int r = t >> 6, ic = t & 63;
    xr[(r * 66) * 72 + ic] = 0;
    xr[(r * 66 + 65) * 72 + ic] = 0;
  }
  __syncthreads();

  const int lane = t & 63, w = t >> 6;
  const int wi = w & 1, wj = w >> 1;  // msub 2*wi.., nsub wj*NSW..
  const int lm = lane & 15, lq = lane >> 4;

  floatx4 acc[2][NSW];
#pragma unroll
  for (int s = 0; s < 2; ++s)
#pragma unroll
    for (int u = 0; u < NSW; ++u) acc[s][u] = floatx4{0.f, 0.f, 0.f, 0.f};

#pragma unroll
  for (int off = 0; off < 9; ++off) {
    const int di = off / 3, dj = off % 3;
#pragma unroll
    for (int kc = 0; kc < 2; ++kc) {
      const int k0 = kc * 32 + lq * 8;
      short8 a[2];
#pragma unroll
      for (int s = 0; s < 2; ++s) {
        int xx = (wi * 2 + s) * 16 + lm;
        a[s] = *(const short8*)&xr[(di * 66 + xx + dj) * 72 + k0];
      }
#pragma unroll
      for (int u = 0; u < NSW; ++u) {
        int oc = (wj * NSW + u) * 16 + lm;
        short8 b = *(const short8*)&wb[((size_t)off * COUT + oc) * 64 + k0];
#pragma unroll
        for (int s = 0; s < 2; ++s) acc[s][u] = MFMA16(a[s], b, acc[s][u]);
      }
    }
  }

  // epilogue: BN + fast_tanh, store NHWC bf16
  unsigned short* outn = outp + (size_t)n * 4096 * COUT;
#pragma unroll
  for (int u = 0; u < NSW; ++u) {
    int oc = (wj * NSW + u) * 16 + lm;
    float sc = gamma[oc] * rsqrtf(var[oc] + 1e-5f);
    float sh = (bias[oc] - mean[oc]) * sc + beta[oc];
#pragma unroll
    for (int s = 0; s < 2; ++s) {
      int m0 = (wi * 2 + s) * 16 + lq * 4;
#pragma unroll
      for (int r = 0; r < 4; ++r) {
        int xx = m0 + r;
        outn[((size_t)y0 * 64 + xx) * COUT + oc] =
            f2bf(fast_tanh(acc[s][u][r] * sc + sh));
      }
    }
  }
}

// ---------------------------------------------------------------------------
// Fused atoms + bases_out + 1x1 coef contraction, MFMA GEMM over K=1024.
// Block: 256 thr, one (n, 8x8 px tile). 16 rounds x 64-K chunks.
// atoms[k][f] register-cached per (px, 4f); As2 double-buffered, 1 barrier
// per round so build(rd+1) VALU overlaps gemm(rd) MFMA.
// ---------------------------------------------------------------------------
__global__ __launch_bounds__(256, 3) void adconv_final(
    const float* __restrict__ x, const unsigned short* __restrict__ bc,
    const float* __restrict__ bases, const unsigned short* __restrict__ coefb,
    float* __restrict__ out) {
  __shared__ union {
    struct {
      unsigned short xs[100 * 68];  // [pos][c], stride 68 (13600 B)
      union {
        float bcs[64 * 100];  // [px][ch] fp32 (25600 B), dead after atoms
        uint4 As2[2 * 64 * 9];  // dbuf [px][8 units + pad] (18432 B)
      } u;
    } s;
    float ot[128 * 68];  // epilogue transpose [oc][px] (34816 B)
  } sm;

  const int t = threadIdx.x;
  const int tile = blockIdx.x;
  const int n = blockIdx.y;
  const int q0 = (tile & 7) * 8, p0 = (tile >> 3) * 8;

  // bases -> uniform regs (SGPRs)
  float bs[54];
#pragma unroll
  for (int i = 0; i < 54; ++i) bs[i] = bases[i];

  // stage x patches as bf16: xs[pos][c]
  const float* xn = x + (size_t)n * 64 * 4096;
#pragma unroll
  for (int it = 0; it < 25; ++it) {
    int idx = it * 256 + t;
    int c = idx / 100;
    int pos = idx - c * 100;
    int r = pos / 10, col = pos - r * 10;
    int gp = p0 - 1 + r, gq = q0 - 1 + col;
    float v = 0.f;
    if ((unsigned)gp < 64u && (unsigned)gq < 64u) v = xn[c * 4096 + gp * 64 + gq];
    sm.s.xs[pos * 68 + c] = f2bf(v);
  }
  // stage bc tile: bcs[px][ch] fp32 from NHWC bf16
  {
    int px = t >> 2, cq3 = t & 3;
    int qx = px >> 3, py = px & 7;
    const unsigned short* bp =
        bc + ((size_t)n * 4096 + (q0 + qx) * 64 + (p0 + py)) * 96 + cq3 * 24;
    float* dst = &sm.s.u.bcs[px * 100 + cq3 * 24];
#pragma unroll
    for (int j = 0; j < 3; ++j) {
      uint4 v = *(const uint4*)(bp + j * 8);
      unsigned int uu[4] = {v.x, v.y, v.z, v.w};
#pragma unroll
      for (int e = 0; e < 4; ++e) {
        dst[j * 8 + e * 2] = bflo(uu[e]);
        dst[j * 8 + e * 2 + 1] = bfhi(uu[e]);
      }
    }
  }
  __syncthreads();

  const int lane = t & 63, w = t >> 6;
  const int wi = w & 1, wj = w >> 1;  // msub 2*wi.., nsub 4*wj..
  const int lm = lane & 15, lq = lane >> 4;
  const int px_a = t >> 2, fq = t & 3;  // A-build role
  const int qx_a = px_a >> 3, py_a = px_a & 7;

  // ---- atoms precompute: at[k][jf] = sum_t bc[(fq*4+jf)*6+t] * bases[t][k]
  float at[9][4];
  {
    const float* brow = &sm.s.u.bcs[px_a * 100 + fq * 24];
    float4 g[6];
#pragma unroll
    for (int m = 0; m < 6; ++m) g[m] = *(const float4*)(brow + m * 4);
    const float* gf = (const float*)g;
#pragma unroll
    for (int jf = 0; jf < 4; ++jf) {
#pragma unroll
      for (int k = 0; k < 9; ++k) {
        float a = 0.f;
#pragma unroll
        for (int tt = 0; tt < 6; ++tt)
          a = fmaf(gf[jf * 6 + tt], bs[tt * 9 + k], a);
        at[k][jf] = a;
      }
    }
  }
  __syncthreads();  // bcs dead; As2 region now writable

  floatx4 acc[2][4];
#pragma unroll
  for (int s = 0; s < 2; ++s)
#pragma unroll
    for (int u = 0; u < 4; ++u) acc[s][u] = floatx4{0.f, 0.f, 0.f, 0.f};

  // build K-chunk r into As2 buffer buf
  auto build = [&](int r, int buf) {
    const int coff = r * 4;  // first c of chunk (elements)
    float a[4][4];
#pragma unroll
    for (int cc = 0; cc < 4; ++cc)
#pragma unroll
      for (int jf = 0; jf < 4; ++jf) a[cc][jf] = 0.f;
#pragma unroll
    for (int i = 0; i < 3; ++i) {
      uint2 pr[3];
#pragma unroll
      for (int j = 0; j < 3; ++j)
        pr[j] = *(const uint2*)&sm.s
                     .xs[((py_a + i) * 10 + qx_a + j) * 68 + coff];
#pragma unroll
      for (int j = 0; j < 3; ++j) {
        int k = i * 3 + j;
        float p0 = bflo(pr[j].x), p1 = bfhi(pr[j].x);
        float p2 = bflo(pr[j].y), p3 = bfhi(pr[j].y);
#pragma unroll
        for (int jf = 0; jf < 4; ++jf) {
          float av = at[k][jf];
          a[0][jf] = fmaf(p0, av, a[0][jf]);
          a[1][jf] = fmaf(p1, av, a[1][jf]);
          a[2][jf] = fmaf(p2, av, a[2][jf]);
          a[3][jf] = fmaf(p3, av, a[3][jf]);
        }
      }
    }
    uint2* dst = (uint2*)&sm.s.u.As2[buf * 576 + px_a * 9];
#pragma unroll
    for (int cc = 0; cc < 4; ++cc) {
      uint2 wv = {packbf2(a[cc][0], a[cc][1]), packbf2(a[cc][2], a[cc][3])};
      dst[(cc * 2 + (fq >> 1)) * 2 + (fq & 1)] = wv;
    }
  };

  auto gemm = [&](int rd, int buf) {
    const uint4* ab = &sm.s.u.As2[buf * 576];
#pragma unroll
    for (int kc = 0; kc < 2; ++kc) {
      short8 a[2];
#pragma unroll
      for (int s = 0; s < 2; ++s) {
        int px = (wi * 2 + s) * 16 + lm;
        a[s] = *(const short8*)&ab[px * 9 + kc * 4 + lq];
      }
#pragma unroll
      for (int u = 0; u < 4; ++u) {
        int oc = (wj * 4 + u) * 16 + lm;
        short8 b = *(const short8*)(coefb + (size_t)oc * 1024 + rd * 64 +
                                    kc * 32 + lq * 8);
        acc[0][u] = MFMA16(a[0], b, acc[0][u]);
        acc[1][u] = MFMA16(a[1], b, acc[1][u]);
      }
    }
  };

  build(0, 0);
  __syncthreads();
  for (int rd = 0; rd < 16; ++rd) {
    if (rd < 15) build(rd + 1, (rd + 1) & 1);
    gemm(rd, rd & 1);
    __syncthreads();
  }

  // ---- epilogue: transpose via LDS, coalesced stores ----
#pragma unroll
  for (int s = 0; s < 2; ++s)
#pragma unroll
    for (int u = 0; u < 4; ++u) {
      int oc = (wj * 4 + u) * 16 + lm;
      int pxb = (wi * 2 + s) * 16 + lq * 4;
#pragma unroll
      for (int r = 0; r < 4; ++r) sm.ot[oc * 68 + pxb + r] = acc[s][u][r];
    }
  __syncthreads();
  float* outn = out + (size_t)n * 128 * 4096;
#pragma unroll
  for (int i = 0; i < 4; ++i) {
    int cid = i * 256 + t;  // 128 oc x 8 qx
    int oc = cid >> 3, qx = cid & 7;
    float4 v0 = *(float4*)&sm.ot[oc * 68 + qx * 8];
    float4 v1 = *(float4*)&sm.ot[oc * 68 + qx * 8 + 4];
    float* op = &outn[((size_t)oc * 64 + q0 + qx) * 64 + p0];
    *(float4*)op = v0;
    *(float4*)(op + 4) = v1;
  }
}

// ---------------------------------------------------------------------------
extern "C" void kernel_launch(void* const* d_in, const int* in_sizes, int n_in,
                              void* d_out, int out_size, void* d_ws,
                              size_t ws_size, hipStream_t stream) {
  const float* x = (const float*)d_in[0];
  const float* conv1_w = (const float*)d_in[1];
  const float* conv1_b = (const float*)d_in[2];
  const float* bn1_g = (const float*)d_in[3];
  const float* bn1_b = (const float*)d_in[4];
  const float* bn1_m = (const float*)d_in[5];
  const float* bn1_v = (const float*)d_in[6];
  const float* conv2_w = (const float*)d_in[7];
  const float* conv2_b = (const float*)d_in[8];
  const float* bn2_g = (const float*)d_in[9];
  const float* bn2_b = (const float*)d_in[10];
  const float* bn2_m = (const float*)d_in[11];
  const float* bn2_v = (const float*)d_in[12];
  const float* bases = (const float*)d_in[13];
  const float* coef = (const float*)d_in[14];
  float* out = (float*)d_out;

  char* ws = (char*)d_ws;
  unsigned short* h = (unsigned short*)(ws);                // 8,388,608 B
  unsigned short* bc = (unsigned short*)(ws + 8388608);     // 12,582,912 B
  unsigned short* wb1 = (unsigned short*)(ws + 20971520);   // 73,728 B
  unsigned short* wb2 = (unsigned short*)(ws + 21045248);   // 110,592 B
  unsigned short* coefb = (unsigned short*)(ws + 21155840); // 262,144 B

  prep_kernel<<<512, 256, 0, stream>>>(conv1_w, conv2_w, coef, wb1, wb2, coefb);
  conv_mfma<64, 2, true><<<dim3(64, NBATCH), 256, 0, stream>>>(
      x, wb1, conv1_b, bn1_g, bn1_b, bn1_m, bn1_v, h);
  conv_mfma<96, 3, false><<<dim3(64, NBATCH), 256, 0, stream>>>(
      h, wb2, conv2_b, bn2_g, bn2_b, bn2_m, bn2_v, bc);
  adconv_final<<<dim3(64, NBATCH), 256, 0, stream>>>(x, bc, bases, coefb, out);
}